// Round 4
// baseline (386.380 us; speedup 1.0000x reference)
//
#include <hip/hip_runtime.h>
#include <math.h>

#define NTOK 4096
#define HDIM 1024
#define NEXP 8
#define IDIM 1408
#define TWO_I 2816
#define TM 256            // gemm1 output tile M = N
#define TK 64             // K-tile depth
#define NRB 40            // 256-row blocks: 8192 real + 8*255 pad <= 10240
#define ROWCAP (NRB * 256)

#define RT_BLKS 1024      // router blocks in moe_rcv
#define CVG_BLKS 2048     // gup-convert blocks in moe_rcv
#define G1_BLKS 440       // gemm blocks in moe_gemm1cd
#define CVD_BLKS 256      // down-convert tail blocks in moe_gemm1cd

typedef _Float16 f16x8 __attribute__((ext_vector_type(8)));
typedef float f32x4 __attribute__((ext_vector_type(4)));

typedef __attribute__((address_space(1))) const unsigned int gu32;
typedef __attribute__((address_space(3))) unsigned int lu32;
__device__ __forceinline__ void async16(const void* g, void* l) {
  __builtin_amdgcn_global_load_lds((gu32*)g, (lu32*)l, 16, 0, 0);
}

// 256-aligned segment prefix from counts (uniform scalar work, once per block)
__device__ __forceinline__ void seg_prefix(const int* __restrict__ counts, int* aof) {
  int o = 0; aof[0] = 0;
#pragma unroll
  for (int i = 0; i < 8; i++) { o += (counts[i] + 255) & ~255; aof[i + 1] = o; }
}

__device__ __forceinline__ void cvt8(const float4* __restrict__ s, uint4* __restrict__ d, size_t idx) {
  float4 a = s[idx * 2], b = s[idx * 2 + 1];
  union { _Float16 h[8]; uint4 u; } p;
  p.h[0] = (_Float16)a.x; p.h[1] = (_Float16)a.y; p.h[2] = (_Float16)a.z; p.h[3] = (_Float16)a.w;
  p.h[4] = (_Float16)b.x; p.h[5] = (_Float16)b.y; p.h[6] = (_Float16)b.z; p.h[7] = (_Float16)b.w;
  d[idx] = p.u;
}

extern "C" __global__ void moe_init(int* counts, int* cursor, int* tok) {
  int i = blockIdx.x * 256 + threadIdx.x;
  if (i < NEXP) { counts[i] = 0; cursor[i] = 0; }
  if (i < ROWCAP) tok[i] = -1;
}

#define NG8 (NEXP * TWO_I * HDIM / 8)   // 2883584
#define ND8 (NEXP * HDIM * IDIM / 8)    // 1441792

// Fused: router (blocks 0..1023; one wave per token: fp32 logits, softmax, top-2,
// fp16 x write, per-token count atomics) + gate_up fp32->fp16 convert (blocks
// 1024.., grid-stride). The convert traffic (138 MB) overlaps router VALU work.
extern "C" __global__ void moe_rcv(const float* __restrict__ x,
                                   const float* __restrict__ rw,
                                   int* __restrict__ topi,
                                   float* __restrict__ topw,
                                   _Float16* __restrict__ xh,
                                   int* __restrict__ counts,
                                   const float* __restrict__ gup,
                                   _Float16* __restrict__ guph) {
  if (blockIdx.x >= RT_BLKS) {
    size_t idx = (size_t)(blockIdx.x - RT_BLKS) * 256 + threadIdx.x;
    const float4* s = (const float4*)gup; uint4* d = (uint4*)guph;
    for (; idx < NG8; idx += (size_t)CVG_BLKS * 256) cvt8(s, d, idx);
    return;
  }
  int w = threadIdx.x >> 6, lane = threadIdx.x & 63;
  int t = blockIdx.x * 4 + w;
  const float4* xp = (const float4*)(x + (size_t)t * HDIM);
  const float4* rp = (const float4*)rw;
  float acc[NEXP];
#pragma unroll
  for (int e = 0; e < NEXP; e++) acc[e] = 0.f;
#pragma unroll
  for (int i = 0; i < HDIM / 256; i++) {  // 4 iters
    float4 xv = xp[i * 64 + lane];
    union { _Float16 h[4]; uint2 u; } pk;
    pk.h[0] = (_Float16)xv.x; pk.h[1] = (_Float16)xv.y;
    pk.h[2] = (_Float16)xv.z; pk.h[3] = (_Float16)xv.w;
    *(uint2*)(xh + (size_t)t * HDIM + i * 256 + lane * 4) = pk.u;
#pragma unroll
    for (int e = 0; e < NEXP; e++) {
      float4 rv = rp[e * 256 + i * 64 + lane];
      acc[e] += xv.x * rv.x + xv.y * rv.y + xv.z * rv.z + xv.w * rv.w;
    }
  }
#pragma unroll
  for (int e = 0; e < NEXP; e++) {
#pragma unroll
    for (int off = 32; off > 0; off >>= 1) acc[e] += __shfl_down(acc[e], off);
  }
  if (lane == 0) {
    float m = acc[0];
    for (int e = 1; e < NEXP; e++) m = fmaxf(m, acc[e]);
    float p[NEXP], s = 0.f;
    for (int e = 0; e < NEXP; e++) { p[e] = __expf(acc[e] - m); s += p[e]; }
    float inv = 1.f / s;
    int i0 = 0; float b0 = p[0];
    for (int e = 1; e < NEXP; e++) if (p[e] > b0) { b0 = p[e]; i0 = e; }
    int i1 = -1; float b1 = -1.f;
    for (int e = 0; e < NEXP; e++) if (e != i0 && p[e] > b1) { b1 = p[e]; i1 = e; }
    topi[t * 2] = i0; topi[t * 2 + 1] = i1;
    topw[t * 2] = b0 * inv; topw[t * 2 + 1] = b1 * inv;
    atomicAdd(&counts[i0], 1);
    atomicAdd(&counts[i1], 1);
  }
}

// block-aggregated scatter: LDS rank + 8 global atomics per block; aof inline
extern "C" __global__ void moe_scatter(const int* __restrict__ topi, const float* __restrict__ topw,
                                       const int* __restrict__ counts, int* __restrict__ cursor,
                                       int* __restrict__ tok, float* __restrict__ wrow,
                                       int* __restrict__ rows) {
  __shared__ int cnt[NEXP];
  __shared__ int base[NEXP];
  int aof[9]; seg_prefix(counts, aof);
  int tid = threadIdx.x;
  if (tid < NEXP) cnt[tid] = 0;
  __syncthreads();
  int t = blockIdx.x * 256 + tid;
  int e0 = topi[t * 2], e1 = topi[t * 2 + 1];
  int r0 = atomicAdd(&cnt[e0], 1);
  int r1 = atomicAdd(&cnt[e1], 1);
  __syncthreads();
  if (tid < NEXP) base[tid] = atomicAdd(&cursor[tid], cnt[tid]);
  __syncthreads();
  int row0 = aof[e0] + base[e0] + r0;
  int row1 = aof[e1] + base[e1] + r1;
  tok[row0] = t; wrow[row0] = topw[t * 2];     rows[t * 2]     = row0;
  tok[row1] = t; wrow[row1] = topw[t * 2 + 1]; rows[t * 2 + 1] = row1;
}

// ---------------- 256x256 8-phase GEMM core (round-2 best: 87.1 us) ----------------
#define WAITVM(n) asm volatile("s_waitcnt vmcnt(" #n ")" ::: "memory")
#define BAR() __builtin_amdgcn_s_barrier()
#define PRIO(x) __builtin_amdgcn_s_setprio(x)

#define LDV(off) (*(const f16x8*)((const char*)smem + (uint32_t)(off)))

#define RD_A(grp, BO) { \
  _Pragma("unroll") for (int m_ = 0; m_ < 4; m_++) { \
    va[m_][0] = LDV(sA0 + (BO) + ((grp)*4 + m_)*2048); \
    va[m_][1] = LDV(sA1 + (BO) + ((grp)*4 + m_)*2048); } }

#define RD_B(VB, nb, BO) { \
  _Pragma("unroll") for (int n_ = 0; n_ < 2; n_++) { \
    VB[n_][0] = LDV(sB0 + (BO) + ((nb)*2 + n_)*2048); \
    VB[n_][1] = LDV(sB1 + (BO) + ((nb)*2 + n_)*2048); } }

#define MM(qa, qb, VB) { \
  _Pragma("unroll") for (int k_ = 0; k_ < 2; k_++) \
  _Pragma("unroll") for (int m_ = 0; m_ < 4; m_++) \
  _Pragma("unroll") for (int n_ = 0; n_ < 2; n_++) \
    acc[(qa)*4 + m_][(qb)*2 + n_] = __builtin_amdgcn_mfma_f32_16x16x32_f16( \
        va[m_][k_], VB[n_][k_], acc[(qa)*4 + m_][(qb)*2 + n_], 0, 0, 0); }

#define STG4(P, bf, r0, kt) { \
  async16(P[0][0] + (kt)*TK, smem + ((bf)*4 + (r0))*8192 + wv*512); \
  async16(P[0][1] + (kt)*TK, smem + ((bf)*4 + (r0))*8192 + 4096 + wv*512); \
  async16(P[1][0] + (kt)*TK, smem + ((bf)*4 + (r0) + 1)*8192 + wv*512); \
  async16(P[1][1] + (kt)*TK, smem + ((bf)*4 + (r0) + 1)*8192 + 4096 + wv*512); }
#define STAGE_A(bf, kt) STG4(pA, bf, 0, kt)
#define STAGE_B(bf, kt) STG4(pB, bf, 2, kt)

#define GEMM_CORE(NIT) { \
  STAGE_B(0, 0); STAGE_A(0, 0); \
  STAGE_B(1, 1); STAGE_A(1, 1); \
  WAITVM(8); BAR(); \
  _Pragma("unroll 1") \
  for (int it = 0; it < (NIT); ++it) { \
    const int nl = (it + 1 < (NIT)); \
    const int kt2 = 2*it + 2, kt3 = 2*it + 3; \
    /* ph0 */ RD_B(vb0, 0, 0); RD_A(0, 0); BAR(); PRIO(1); MM(0,0,vb0); PRIO(0); BAR(); \
    /* ph1 */ RD_B(vb1, 1, 0); BAR(); PRIO(1); MM(0,1,vb1); PRIO(0); BAR(); \
    /* ph2 */ RD_A(1, 0); if (nl) STAGE_B(0, kt2); BAR(); PRIO(1); MM(1,0,vb0); PRIO(0); BAR(); \
    /* ph3 */ if (nl) { STAGE_A(0, kt2); } PRIO(1); MM(1,1,vb1); PRIO(0); \
              if (nl) { WAITVM(8); } else { WAITVM(0); } BAR(); \
    /* ph4 */ RD_B(vb0, 0, 65536); RD_A(0, 65536); BAR(); PRIO(1); MM(0,0,vb0); PRIO(0); BAR(); \
    /* ph5 */ RD_B(vb1, 1, 65536); BAR(); PRIO(1); MM(0,1,vb1); PRIO(0); BAR(); \
    /* ph6 */ RD_A(1, 65536); if (nl) STAGE_B(1, kt3); BAR(); PRIO(1); MM(1,0,vb0); PRIO(0); BAR(); \
    /* ph7 */ if (nl) { STAGE_A(1, kt3); } PRIO(1); MM(1,1,vb1); PRIO(0); \
              if (nl) { WAITVM(8); } BAR(); \
  } \
  asm volatile("" ::: "memory"); }

#define GEMM_SETUP() \
  const int lane = tid & 63, wv = tid >> 6; \
  const int wm = wv >> 2, wn = wv & 3; \
  const int quad = lane >> 4, l15 = lane & 15; \
  const int srow = tid >> 3; \
  const int kc = ((tid & 7) ^ (srow & 7)) << 3; \
  const uint32_t c0 = (uint32_t)((quad * 16) ^ ((l15 & 7) << 4)); \
  const uint32_t c1 = c0 ^ 64; \
  const uint32_t sA0 = wm * 16384 + l15 * 128 + c0; \
  const uint32_t sA1 = wm * 16384 + l15 * 128 + c1; \
  const uint32_t sB0 = (2 + (wn >> 1)) * 16384 + ((wn & 1) * 64 + l15) * 128 + c0; \
  const uint32_t sB1 = (2 + (wn >> 1)) * 16384 + ((wn & 1) * 64 + l15) * 128 + c1; \
  f32x4 acc[8][4]; \
  _Pragma("unroll") for (int m = 0; m < 8; m++) \
  _Pragma("unroll") for (int n = 0; n < 4; n++) acc[m][n] = (f32x4){0.f, 0.f, 0.f, 0.f}; \
  f16x8 va[4][2], vb0[2][2], vb1[2][2];

// GEMM1 + down-convert tail. Gemm blocks 0..439 (8 XCD-groups x (11 j x 5 r5));
// blocks 440.. grid-stride convert down_proj fp32->fp16 — they dispatch after
// the gemm blocks and mop up CUs freed in gemm1's second scheduling round.
extern "C" __global__ __launch_bounds__(512, 2) void moe_gemm1cd(
    const _Float16* __restrict__ xh, const _Float16* __restrict__ guph,
    const int* __restrict__ counts, const int* __restrict__ tok,
    _Float16* __restrict__ hbuf,
    const float* __restrict__ dp, _Float16* __restrict__ dph) {
  __shared__ __align__(128) _Float16 smem[65536];  // 128 KiB
  const int tid = threadIdx.x;
  const int fid = blockIdx.x;
  if (fid >= G1_BLKS) {
    size_t idx = (size_t)(fid - G1_BLKS) * 512 + tid;
    const float4* s = (const float4*)dp; uint4* d = (uint4*)dph;
    for (; idx < ND8; idx += (size_t)CVD_BLKS * 512) cvt8(s, d, idx);
    return;
  }
  int aof[9]; seg_prefix(counts, aof);
  const int g = fid & 7, t7 = fid >> 3;   // t7 in [0,55)
  const int j = t7 / 5, r5 = t7 - j * 5;  // j 0..10
  const int rb = g + 8 * r5;
  const int row0 = rb * TM;
  if (row0 >= aof[8]) return;
  int e = 0;
#pragma unroll
  for (int i = 0; i < 8; i++) if (row0 >= aof[i]) e = i;

  GEMM_SETUP();

  const _Float16* pA[2][2]; const _Float16* pB[2][2];
#pragma unroll
  for (int h = 0; h < 2; h++)
#pragma unroll
    for (int q = 0; q < 2; q++) {
      int tk = tok[row0 + h * 128 + q * 64 + srow];
      tk = tk < 0 ? 0 : tk;                 // pad rows clamp; outputs discarded
      pA[h][q] = xh + (size_t)tk * HDIM + kc;
    }
  const _Float16* eb = guph + (size_t)e * TWO_I * HDIM;
#pragma unroll
  for (int q = 0; q < 2; q++) {
    pB[0][q] = eb + (size_t)(j * 128 + q * 64 + srow) * HDIM + kc;          // gate
    pB[1][q] = eb + (size_t)(IDIM + j * 128 + q * 64 + srow) * HDIM + kc;   // up
  }

  GEMM_CORE(HDIM / (2 * TK))   // 8 iters (16 K-tiles)

  // epilogue: up-waves (wn>=2) park u in LDS; gate-waves compute silu(g)*u
  if (wn >= 2) {
#pragma unroll
    for (int mf = 0; mf < 8; mf++)
#pragma unroll
      for (int nf = 0; nf < 4; nf++)
#pragma unroll
        for (int r2 = 0; r2 < 4; r2++)
          smem[(wm * 128 + mf * 16 + quad * 4 + r2) * 132 + (wn - 2) * 64 + nf * 16 + l15] =
              (_Float16)acc[mf][nf][r2];
  }
  __syncthreads();
  if (wn < 2) {
#pragma unroll
    for (int mf = 0; mf < 8; mf++) {
#pragma unroll
      for (int r2 = 0; r2 < 4; r2++) {
        const int rl = wm * 128 + mf * 16 + quad * 4 + r2;
        _Float16* orow = hbuf + (size_t)(row0 + rl) * IDIM + j * 128 + wn * 64;
#pragma unroll
        for (int nf = 0; nf < 4; nf++) {
          float gg = acc[mf][nf][r2];
          float uu = (float)smem[rl * 132 + wn * 64 + nf * 16 + l15];
          float hh = gg / (1.f + __expf(-gg)) * uu;
          orow[nf * 16 + l15] = (_Float16)hh;
        }
      }
    }
  }
}

// ---------------- GEMM2: 128x128 tile, BK=64, 4 waves, 64 KB LDS -> 2 blocks/CU ----
// y[row, 1024] = (h @ down[e]^T) * wrow[row]; fp16 out to yh (no atomics).
// TLP across 2 independent co-resident blocks replaces intra-block pipelining.
// Grid 640 = 8 XCD-groups x (8 cb x 10 r10); rb = g + 8*r10 covers 80 rb (ROWCAP).
// LDS per buf: A[128][64] 16 KB + B[128][64] 16 KB; double-buffered = 64 KB.
// Same XOR swizzle: 16B slot s of row r holds source chunk s^(r&7).
extern "C" __global__ __launch_bounds__(256, 2) void moe_gemm2(
    const _Float16* __restrict__ hbuf, const _Float16* __restrict__ dph,
    const int* __restrict__ counts, const float* __restrict__ wrow,
    _Float16* __restrict__ yh) {
  __shared__ __align__(128) _Float16 smem[32768];  // 64 KiB
  int aof[9]; seg_prefix(counts, aof);
  const int fid = blockIdx.x;
  const int g = fid & 7, t7 = fid >> 3;       // t7 in [0,80)
  const int cb = t7 / 10, r10 = t7 - cb * 10; // cb 0..7
  const int rb = g + 8 * r10;                 // 0..79
  const int row0 = rb * 128;
  if (row0 >= aof[8]) return;
  int e = 0;
#pragma unroll
  for (int i = 0; i < 8; i++) if (row0 >= aof[i]) e = i;

  const int tid = threadIdx.x;
  const int lane = tid & 63, wv = tid >> 6;   // 4 waves
  const int wm = wv >> 1, wn = wv & 1;        // 2M x 2N, wave-tile 64x64
  const int quad = lane >> 4, l15 = lane & 15;
  const int kc = ((tid & 7) ^ ((tid >> 3) & 7)) << 3;
  const uint32_t c0 = (uint32_t)((quad * 16) ^ ((l15 & 7) << 4));
  const uint32_t c1 = c0 ^ 64;
  const uint32_t sA_0 = (uint32_t)((wm * 64 + l15) * 128) + c0;
  const uint32_t sA_1 = (uint32_t)((wm * 64 + l15) * 128) + c1;
  const uint32_t sB_0 = 16384u + (uint32_t)((wn * 64 + l15) * 128) + c0;
  const uint32_t sB_1 = 16384u + (uint32_t)((wn * 64 + l15) * 128) + c1;

  f32x4 acc2[4][4];
#pragma unroll
  for (int m = 0; m < 4; m++)
#pragma unroll
    for (int n = 0; n < 4; n++) acc2[m][n] = (f32x4){0.f, 0.f, 0.f, 0.f};
  f16x8 va2[4][2], vb2[4][2];

  const _Float16* pA2[4]; const _Float16* pB2[4];
  const _Float16* eb = dph + (size_t)e * HDIM * IDIM;
#pragma unroll
  for (int c = 0; c < 4; c++) {
    pA2[c] = hbuf + (size_t)(row0 + c * 32 + (tid >> 3)) * IDIM + kc;
    pB2[c] = eb + (size_t)(cb * 128 + c * 32 + (tid >> 3)) * IDIM + kc;
  }

#define STG2(bf, kt) { \
  _Pragma("unroll") for (int c_ = 0; c_ < 4; c_++) { \
    async16(pA2[c_] + (kt)*TK, smem + (bf)*16384 + c_*2048 + tid*8); \
    async16(pB2[c_] + (kt)*TK, smem + (bf)*16384 + 8192 + c_*2048 + tid*8); } }

  const int NIT2 = IDIM / TK;  // 22
  STG2(0, 0); STG2(1, 1);
  WAITVM(8); BAR();
#pragma unroll 1
  for (int kt = 0; kt < NIT2; ++kt) {
    const uint32_t BO = (kt & 1) ? 32768u : 0u;
#pragma unroll
    for (int m_ = 0; m_ < 4; m_++) {
      va2[m_][0] = LDV(sA_0 + BO + m_ * 2048);
      va2[m_][1] = LDV(sA_1 + BO + m_ * 2048);
    }
#pragma unroll
    for (int n_ = 0; n_ < 4; n_++) {
      vb2[n_][0] = LDV(sB_0 + BO + n_ * 2048);
      vb2[n_][1] = LDV(sB_1 + BO + n_ * 2048);
    }
    asm volatile("s_waitcnt lgkmcnt(0)" ::: "memory");
    BAR();
    if (kt + 2 < NIT2) { STG2((kt & 1), kt + 2); }
    PRIO(1);
#pragma unroll
    for (int k_ = 0; k_ < 2; k_++)
#pragma unroll
      for (int m_ = 0; m_ < 4; m_++)
#pragma unroll
        for (int n_ = 0; n_ < 4; n_++)
          acc2[m_][n_] = __builtin_amdgcn_mfma_f32_16x16x32_f16(
              va2[m_][k_], vb2[n_][k_], acc2[m_][n_], 0, 0, 0);
    PRIO(0);
    if (kt + 2 < NIT2) { WAITVM(8); } else { WAITVM(0); }
    BAR();
  }
#undef STG2

#pragma unroll
  for (int mf = 0; mf < 4; mf++) {
#pragma unroll
    for (int r2 = 0; r2 < 4; r2++) {
      const int row = row0 + wm * 64 + mf * 16 + quad * 4 + r2;
      const float wgt = wrow[row];  // pad rows: finite poison, never read back
      _Float16* orow = yh + (size_t)row * HDIM + cb * 128 + wn * 64;
#pragma unroll
      for (int nf = 0; nf < 4; nf++)
        orow[nf * 16 + l15] = (_Float16)(acc2[mf][nf][r2] * wgt);
    }
  }
}

// out[t, :] = y[rowA(t), :] + y[rowB(t), :]
extern "C" __global__ void moe_combine(const _Float16* __restrict__ yh,
                                       const int* __restrict__ rows,
                                       float* __restrict__ out) {
  int i = blockIdx.x * 256 + threadIdx.x;  // over T*H/8 = 524288
  int t = i >> 7, c8 = i & 127;
  int rA = rows[t * 2], rB = rows[t * 2 + 1];
  union { uint4 u; _Float16 h[8]; } pa, pb;
  pa.u = ((const uint4*)(yh + (size_t)rA * HDIM))[c8];
  pb.u = ((const uint4*)(yh + (size_t)rB * HDIM))[c8];
  float4 o0, o1;
  o0.x = (float)pa.h[0] + (float)pb.h[0]; o0.y = (float)pa.h[1] + (float)pb.h[1];
  o0.z = (float)pa.h[2] + (float)pb.h[2]; o0.w = (float)pa.h[3] + (float)pb.h[3];
  o1.x = (float)pa.h[4] + (float)pb.h[4]; o1.y = (float)pa.h[5] + (float)pb.h[5];
  o1.z = (float)pa.h[6] + (float)pb.h[6]; o1.w = (float)pa.h[7] + (float)pb.h[7];
  ((float4*)out)[(size_t)i * 2] = o0;
  ((float4*)out)[(size_t)i * 2 + 1] = o1;
}

extern "C" void kernel_launch(void* const* d_in, const int* in_sizes, int n_in,
                              void* d_out, int out_size, void* d_ws, size_t ws_size,
                              hipStream_t stream) {
  const float* x   = (const float*)d_in[0];  // [4096,1024]
  const float* rw  = (const float*)d_in[1];  // [8,1024]
  const float* gup = (const float*)d_in[2];  // [8,2816,1024]
  const float* dp  = (const float*)d_in[3];  // [8,1024,1408]
  float* out = (float*)d_out;

  char* ws = (char*)d_ws;
  int*   counts = (int*)ws;                       // @0
  int*   cursor = (int*)(ws + 64);
  int*   topi   = (int*)(ws + 4096);              // 8192 ints
  float* topw   = (float*)(ws + 36864);           // 8192 floats
  int*   tok    = (int*)(ws + 69632);             // 10240 ints  -> 110592
  float* wrow   = (float*)(ws + 110592);          // 10240 floats-> 151552
  int*   rows   = (int*)(ws + 151552);            // 8192 ints   -> 184320
  _Float16* xh   = (_Float16*)(ws + 184320);      // 8.39 MB  -> 8572928
  _Float16* guph = (_Float16*)(ws + 8572928);     // 46.14 MB -> 54710272
  _Float16* dph  = (_Float16*)(ws + 54710272);    // 23.07 MB -> 77778944
  _Float16* hbuf = (_Float16*)(ws + 77778944);    // 28.84 MB -> 106614784 (total 106.6 MB)
  _Float16* yh   = (_Float16*)(ws + 8572928);     // aliases guph (dead after gemm1)

  moe_init<<<(ROWCAP + 255) / 256, 256, 0, stream>>>(counts, cursor, tok);
  moe_rcv<<<RT_BLKS + CVG_BLKS, 256, 0, stream>>>(x, rw, topi, topw, xh, counts, gup, guph);
  moe_scatter<<<NTOK / 256, 256, 0, stream>>>(topi, topw, counts, cursor, tok, wrow, rows);
  moe_gemm1cd<<<G1_BLKS + CVD_BLKS, 512, 0, stream>>>(xh, guph, counts, tok, hbuf, dp, dph);
  moe_gemm2<<<8 * 8 * 10, 256, 0, stream>>>(hbuf, dph, counts, wrow, yh);
  moe_combine<<<NTOK * HDIM / 8 / 256, 256, 0, stream>>>(yh, rows, out);
}

// Round 5
// 317.081 us; speedup vs baseline: 1.2186x; 1.2186x over previous
//
#include <hip/hip_runtime.h>
#include <math.h>

#define NTOK 4096
#define HDIM 1024
#define NEXP 8
#define IDIM 1408
#define TWO_I 2816
#define TM 256            // gemm1 output tile M = N
#define TK 64             // K-tile depth
#define NRB 40            // 256-row blocks: 8192 real + 8*255 pad <= 10240
#define ROWCAP (NRB * 256)

#define RT_BLKS 1024      // router blocks in moe_rcv
#define CVG_BLKS 2048     // gup-convert blocks in moe_rcv
#define G1_BLKS 440       // gemm blocks in moe_gemm1cd
#define CVD_BLKS 256      // down-convert tail blocks in moe_gemm1cd

typedef _Float16 f16x8 __attribute__((ext_vector_type(8)));
typedef float f32x4 __attribute__((ext_vector_type(4)));

typedef __attribute__((address_space(1))) const unsigned int gu32;
typedef __attribute__((address_space(3))) unsigned int lu32;
__device__ __forceinline__ void async16(const void* g, void* l) {
  __builtin_amdgcn_global_load_lds((gu32*)g, (lu32*)l, 16, 0, 0);
}

// 256-aligned segment prefix from counts (uniform scalar work, once per block)
__device__ __forceinline__ void seg_prefix(const int* __restrict__ counts, int* aof) {
  int o = 0; aof[0] = 0;
#pragma unroll
  for (int i = 0; i < 8; i++) { o += (counts[i] + 255) & ~255; aof[i + 1] = o; }
}

__device__ __forceinline__ void cvt8(const float4* __restrict__ s, uint4* __restrict__ d, size_t idx) {
  float4 a = s[idx * 2], b = s[idx * 2 + 1];
  union { _Float16 h[8]; uint4 u; } p;
  p.h[0] = (_Float16)a.x; p.h[1] = (_Float16)a.y; p.h[2] = (_Float16)a.z; p.h[3] = (_Float16)a.w;
  p.h[4] = (_Float16)b.x; p.h[5] = (_Float16)b.y; p.h[6] = (_Float16)b.z; p.h[7] = (_Float16)b.w;
  d[idx] = p.u;
}

#define NG8 (NEXP * TWO_I * HDIM / 8)   // 2883584
#define ND8 (NEXP * HDIM * IDIM / 8)    // 1441792

// Fused: router (blocks 0..1023; one wave per token: fp32 logits, softmax, top-2,
// fp16 x write — NO count atomics) + gate_up fp32->fp16 convert (blocks 1024..,
// grid-stride). Round-4 lesson: per-token device atomics on one cache line
// serialized at ~15ns each -> 123us; counting moved back to LDS-aggregated kernel.
extern "C" __global__ void moe_rcv(const float* __restrict__ x,
                                   const float* __restrict__ rw,
                                   int* __restrict__ topi,
                                   float* __restrict__ topw,
                                   _Float16* __restrict__ xh,
                                   const float* __restrict__ gup,
                                   _Float16* __restrict__ guph) {
  if (blockIdx.x >= RT_BLKS) {
    size_t idx = (size_t)(blockIdx.x - RT_BLKS) * 256 + threadIdx.x;
    const float4* s = (const float4*)gup; uint4* d = (uint4*)guph;
    for (; idx < NG8; idx += (size_t)CVG_BLKS * 256) cvt8(s, d, idx);
    return;
  }
  int w = threadIdx.x >> 6, lane = threadIdx.x & 63;
  int t = blockIdx.x * 4 + w;
  const float4* xp = (const float4*)(x + (size_t)t * HDIM);
  const float4* rp = (const float4*)rw;
  float acc[NEXP];
#pragma unroll
  for (int e = 0; e < NEXP; e++) acc[e] = 0.f;
#pragma unroll
  for (int i = 0; i < HDIM / 256; i++) {  // 4 iters
    float4 xv = xp[i * 64 + lane];
    union { _Float16 h[4]; uint2 u; } pk;
    pk.h[0] = (_Float16)xv.x; pk.h[1] = (_Float16)xv.y;
    pk.h[2] = (_Float16)xv.z; pk.h[3] = (_Float16)xv.w;
    *(uint2*)(xh + (size_t)t * HDIM + i * 256 + lane * 4) = pk.u;
#pragma unroll
    for (int e = 0; e < NEXP; e++) {
      float4 rv = rp[e * 256 + i * 64 + lane];
      acc[e] += xv.x * rv.x + xv.y * rv.y + xv.z * rv.z + xv.w * rv.w;
    }
  }
#pragma unroll
  for (int e = 0; e < NEXP; e++) {
#pragma unroll
    for (int off = 32; off > 0; off >>= 1) acc[e] += __shfl_down(acc[e], off);
  }
  if (lane == 0) {
    float m = acc[0];
    for (int e = 1; e < NEXP; e++) m = fmaxf(m, acc[e]);
    float p[NEXP], s = 0.f;
    for (int e = 0; e < NEXP; e++) { p[e] = __expf(acc[e] - m); s += p[e]; }
    float inv = 1.f / s;
    int i0 = 0; float b0 = p[0];
    for (int e = 1; e < NEXP; e++) if (p[e] > b0) { b0 = p[e]; i0 = e; }
    int i1 = -1; float b1 = -1.f;
    for (int e = 0; e < NEXP; e++) if (e != i0 && p[e] > b1) { b1 = p[e]; i1 = e; }
    topi[t * 2] = i0; topi[t * 2 + 1] = i1;
    topw[t * 2] = b0 * inv; topw[t * 2 + 1] = b1 * inv;
  }
}

// per-block expert histogram -> plain partial stores (no global atomics, no init)
extern "C" __global__ void moe_count(const int* __restrict__ topi, int* __restrict__ cnt_part) {
  __shared__ int cnt[NEXP];
  if (threadIdx.x < NEXP) cnt[threadIdx.x] = 0;
  __syncthreads();
  int t = blockIdx.x * 256 + threadIdx.x;
  atomicAdd(&cnt[topi[t * 2]], 1);
  atomicAdd(&cnt[topi[t * 2 + 1]], 1);
  __syncthreads();
  if (threadIdx.x < NEXP) cnt_part[blockIdx.x * NEXP + threadIdx.x] = cnt[threadIdx.x];
}

// deterministic scatter: totals/aof/block-prefix computed from partials locally;
// no cursor, no cross-block atomics. Block 0 publishes counts for the GEMMs.
extern "C" __global__ void moe_scatter(const int* __restrict__ topi, const float* __restrict__ topw,
                                       const int* __restrict__ cnt_part, int* __restrict__ counts,
                                       int* __restrict__ tok, float* __restrict__ wrow,
                                       int* __restrict__ rows) {
  __shared__ int part_l[16 * NEXP];
  __shared__ int cnt[NEXP];
  __shared__ int base[NEXP];
  __shared__ int tot_l[NEXP];
  const int tid = threadIdx.x, blk = blockIdx.x;
  if (tid < 16 * NEXP) part_l[tid] = cnt_part[tid];
  if (tid < NEXP) cnt[tid] = 0;
  __syncthreads();
  if (tid < NEXP) {
    int tot = 0, pre = 0;
#pragma unroll
    for (int b = 0; b < 16; b++) {
      int v = part_l[b * NEXP + tid];
      tot += v;
      if (b < blk) pre += v;
    }
    tot_l[tid] = tot;
    base[tid] = pre;
  }
  __syncthreads();
  if (tid < NEXP) {
    int o = 0;
    for (int i = 0; i < tid; i++) o += (tot_l[i] + 255) & ~255;   // aof[e]
    base[tid] += o;
    if (blk == 0) counts[tid] = tot_l[tid];
  }
  __syncthreads();
  int t = blk * 256 + tid;
  int e0 = topi[t * 2], e1 = topi[t * 2 + 1];
  int r0 = atomicAdd(&cnt[e0], 1);
  int r1 = atomicAdd(&cnt[e1], 1);
  int row0 = base[e0] + r0;
  int row1 = base[e1] + r1;
  tok[row0] = t; wrow[row0] = topw[t * 2];     rows[t * 2]     = row0;
  tok[row1] = t; wrow[row1] = topw[t * 2 + 1]; rows[t * 2 + 1] = row1;
}

// ---------------- 256x256 8-phase GEMM core (round-2 best: 87.1 us) ----------------
#define WAITVM(n) asm volatile("s_waitcnt vmcnt(" #n ")" ::: "memory")
#define BAR() __builtin_amdgcn_s_barrier()
#define PRIO(x) __builtin_amdgcn_s_setprio(x)

#define LDV(off) (*(const f16x8*)((const char*)smem + (uint32_t)(off)))

#define RD_A(grp, BO) { \
  _Pragma("unroll") for (int m_ = 0; m_ < 4; m_++) { \
    va[m_][0] = LDV(sA0 + (BO) + ((grp)*4 + m_)*2048); \
    va[m_][1] = LDV(sA1 + (BO) + ((grp)*4 + m_)*2048); } }

#define RD_B(VB, nb, BO) { \
  _Pragma("unroll") for (int n_ = 0; n_ < 2; n_++) { \
    VB[n_][0] = LDV(sB0 + (BO) + ((nb)*2 + n_)*2048); \
    VB[n_][1] = LDV(sB1 + (BO) + ((nb)*2 + n_)*2048); } }

#define MM(qa, qb, VB) { \
  _Pragma("unroll") for (int k_ = 0; k_ < 2; k_++) \
  _Pragma("unroll") for (int m_ = 0; m_ < 4; m_++) \
  _Pragma("unroll") for (int n_ = 0; n_ < 2; n_++) \
    acc[(qa)*4 + m_][(qb)*2 + n_] = __builtin_amdgcn_mfma_f32_16x16x32_f16( \
        va[m_][k_], VB[n_][k_], acc[(qa)*4 + m_][(qb)*2 + n_], 0, 0, 0); }

#define STG4(P, bf, r0, kt) { \
  async16(P[0][0] + (kt)*TK, smem + ((bf)*4 + (r0))*8192 + wv*512); \
  async16(P[0][1] + (kt)*TK, smem + ((bf)*4 + (r0))*8192 + 4096 + wv*512); \
  async16(P[1][0] + (kt)*TK, smem + ((bf)*4 + (r0) + 1)*8192 + wv*512); \
  async16(P[1][1] + (kt)*TK, smem + ((bf)*4 + (r0) + 1)*8192 + 4096 + wv*512); }
#define STAGE_A(bf, kt) STG4(pA, bf, 0, kt)
#define STAGE_B(bf, kt) STG4(pB, bf, 2, kt)

#define GEMM_CORE(NIT) { \
  STAGE_B(0, 0); STAGE_A(0, 0); \
  STAGE_B(1, 1); STAGE_A(1, 1); \
  WAITVM(8); BAR(); \
  _Pragma("unroll 1") \
  for (int it = 0; it < (NIT); ++it) { \
    const int nl = (it + 1 < (NIT)); \
    const int kt2 = 2*it + 2, kt3 = 2*it + 3; \
    /* ph0 */ RD_B(vb0, 0, 0); RD_A(0, 0); BAR(); PRIO(1); MM(0,0,vb0); PRIO(0); BAR(); \
    /* ph1 */ RD_B(vb1, 1, 0); BAR(); PRIO(1); MM(0,1,vb1); PRIO(0); BAR(); \
    /* ph2 */ RD_A(1, 0); if (nl) STAGE_B(0, kt2); BAR(); PRIO(1); MM(1,0,vb0); PRIO(0); BAR(); \
    /* ph3 */ if (nl) { STAGE_A(0, kt2); } PRIO(1); MM(1,1,vb1); PRIO(0); \
              if (nl) { WAITVM(8); } else { WAITVM(0); } BAR(); \
    /* ph4 */ RD_B(vb0, 0, 65536); RD_A(0, 65536); BAR(); PRIO(1); MM(0,0,vb0); PRIO(0); BAR(); \
    /* ph5 */ RD_B(vb1, 1, 65536); BAR(); PRIO(1); MM(0,1,vb1); PRIO(0); BAR(); \
    /* ph6 */ RD_A(1, 65536); if (nl) STAGE_B(1, kt3); BAR(); PRIO(1); MM(1,0,vb0); PRIO(0); BAR(); \
    /* ph7 */ if (nl) { STAGE_A(1, kt3); } PRIO(1); MM(1,1,vb1); PRIO(0); \
              if (nl) { WAITVM(8); } BAR(); \
  } \
  asm volatile("" ::: "memory"); }

#define GEMM_SETUP() \
  const int lane = tid & 63, wv = tid >> 6; \
  const int wm = wv >> 2, wn = wv & 3; \
  const int quad = lane >> 4, l15 = lane & 15; \
  const int srow = tid >> 3; \
  const int kc = ((tid & 7) ^ (srow & 7)) << 3; \
  const uint32_t c0 = (uint32_t)((quad * 16) ^ ((l15 & 7) << 4)); \
  const uint32_t c1 = c0 ^ 64; \
  const uint32_t sA0 = wm * 16384 + l15 * 128 + c0; \
  const uint32_t sA1 = wm * 16384 + l15 * 128 + c1; \
  const uint32_t sB0 = (2 + (wn >> 1)) * 16384 + ((wn & 1) * 64 + l15) * 128 + c0; \
  const uint32_t sB1 = (2 + (wn >> 1)) * 16384 + ((wn & 1) * 64 + l15) * 128 + c1; \
  f32x4 acc[8][4]; \
  _Pragma("unroll") for (int m = 0; m < 8; m++) \
  _Pragma("unroll") for (int n = 0; n < 4; n++) acc[m][n] = (f32x4){0.f, 0.f, 0.f, 0.f}; \
  f16x8 va[4][2], vb0[2][2], vb1[2][2];

// GEMM1 + down-convert tail. Gemm blocks 0..439 (8 XCD-groups x (11 j x 5 r5));
// blocks 440.. grid-stride convert down_proj fp32->fp16 on CUs freed during
// gemm1's second scheduling round. Pad rows detected via lim = aof[e]+counts[e]
// (tok needs no sentinel init; speculative in-bounds load, value cndmask'd).
extern "C" __global__ __launch_bounds__(512, 2) void moe_gemm1cd(
    const _Float16* __restrict__ xh, const _Float16* __restrict__ guph,
    const int* __restrict__ counts, const int* __restrict__ tok,
    _Float16* __restrict__ hbuf,
    const float* __restrict__ dp, _Float16* __restrict__ dph) {
  __shared__ __align__(128) _Float16 smem[65536];  // 128 KiB
  const int tid = threadIdx.x;
  const int fid = blockIdx.x;
  if (fid >= G1_BLKS) {
    size_t idx = (size_t)(fid - G1_BLKS) * 512 + tid;
    const float4* s = (const float4*)dp; uint4* d = (uint4*)dph;
    for (; idx < ND8; idx += (size_t)CVD_BLKS * 512) cvt8(s, d, idx);
    return;
  }
  int aof[9]; seg_prefix(counts, aof);
  const int g = fid & 7, t7 = fid >> 3;   // t7 in [0,55)
  const int j = t7 / 5, r5 = t7 - j * 5;  // j 0..10
  const int rb = g + 8 * r5;
  const int row0 = rb * TM;
  if (row0 >= aof[8]) return;
  int e = 0;
#pragma unroll
  for (int i = 0; i < 8; i++) if (row0 >= aof[i]) e = i;
  const int lim = aof[e] + counts[e];     // rows >= lim are pad

  GEMM_SETUP();

  const _Float16* pA[2][2]; const _Float16* pB[2][2];
#pragma unroll
  for (int h = 0; h < 2; h++)
#pragma unroll
    for (int q = 0; q < 2; q++) {
      int rowi = row0 + h * 128 + q * 64 + srow;
      int tv = tok[rowi];                  // in-bounds always; garbage on pad rows
      int tk = (rowi < lim) ? tv : 0;      // pad rows clamp; outputs discarded
      pA[h][q] = xh + (size_t)tk * HDIM + kc;
    }
  const _Float16* eb = guph + (size_t)e * TWO_I * HDIM;
#pragma unroll
  for (int q = 0; q < 2; q++) {
    pB[0][q] = eb + (size_t)(j * 128 + q * 64 + srow) * HDIM + kc;          // gate
    pB[1][q] = eb + (size_t)(IDIM + j * 128 + q * 64 + srow) * HDIM + kc;   // up
  }

  GEMM_CORE(HDIM / (2 * TK))   // 8 iters (16 K-tiles)

  // epilogue: up-waves (wn>=2) park u in LDS; gate-waves compute silu(g)*u
  if (wn >= 2) {
#pragma unroll
    for (int mf = 0; mf < 8; mf++)
#pragma unroll
      for (int nf = 0; nf < 4; nf++)
#pragma unroll
        for (int r2 = 0; r2 < 4; r2++)
          smem[(wm * 128 + mf * 16 + quad * 4 + r2) * 132 + (wn - 2) * 64 + nf * 16 + l15] =
              (_Float16)acc[mf][nf][r2];
  }
  __syncthreads();
  if (wn < 2) {
#pragma unroll
    for (int mf = 0; mf < 8; mf++) {
#pragma unroll
      for (int r2 = 0; r2 < 4; r2++) {
        const int rl = wm * 128 + mf * 16 + quad * 4 + r2;
        _Float16* orow = hbuf + (size_t)(row0 + rl) * IDIM + j * 128 + wn * 64;
#pragma unroll
        for (int nf = 0; nf < 4; nf++) {
          float gg = acc[mf][nf][r2];
          float uu = (float)smem[rl * 132 + wn * 64 + nf * 16 + l15];
          float hh = gg / (1.f + __expf(-gg)) * uu;
          orow[nf * 16 + l15] = (_Float16)hh;
        }
      }
    }
  }
}

// ---------------- GEMM2: 128x128 tile, BK=64, 4 waves, 64 KB LDS -> 2 blocks/CU ----
// y[row, 1024] = (h @ down[e]^T) * wrow[row]; fp16 out to yh (no atomics).
// Grid 640 = 8 XCD-groups x (8 cb x 10 r10); rb = g + 8*r10 covers 80 rb (ROWCAP).
extern "C" __global__ __launch_bounds__(256, 2) void moe_gemm2(
    const _Float16* __restrict__ hbuf, const _Float16* __restrict__ dph,
    const int* __restrict__ counts, const float* __restrict__ wrow,
    _Float16* __restrict__ yh) {
  __shared__ __align__(128) _Float16 smem[32768];  // 64 KiB
  int aof[9]; seg_prefix(counts, aof);
  const int fid = blockIdx.x;
  const int g = fid & 7, t7 = fid >> 3;       // t7 in [0,80)
  const int cb = t7 / 10, r10 = t7 - cb * 10; // cb 0..7
  const int rb = g + 8 * r10;                 // 0..79
  const int row0 = rb * 128;
  if (row0 >= aof[8]) return;
  int e = 0;
#pragma unroll
  for (int i = 0; i < 8; i++) if (row0 >= aof[i]) e = i;

  const int tid = threadIdx.x;
  const int lane = tid & 63, wv = tid >> 6;   // 4 waves
  const int wm = wv >> 1, wn = wv & 1;        // 2M x 2N, wave-tile 64x64
  const int quad = lane >> 4, l15 = lane & 15;
  const int kc = ((tid & 7) ^ ((tid >> 3) & 7)) << 3;
  const uint32_t c0 = (uint32_t)((quad * 16) ^ ((l15 & 7) << 4));
  const uint32_t c1 = c0 ^ 64;
  const uint32_t sA_0 = (uint32_t)((wm * 64 + l15) * 128) + c0;
  const uint32_t sA_1 = (uint32_t)((wm * 64 + l15) * 128) + c1;
  const uint32_t sB_0 = 16384u + (uint32_t)((wn * 64 + l15) * 128) + c0;
  const uint32_t sB_1 = 16384u + (uint32_t)((wn * 64 + l15) * 128) + c1;

  f32x4 acc2[4][4];
#pragma unroll
  for (int m = 0; m < 4; m++)
#pragma unroll
    for (int n = 0; n < 4; n++) acc2[m][n] = (f32x4){0.f, 0.f, 0.f, 0.f};
  f16x8 va2[4][2], vb2[4][2];

  const _Float16* pA2[4]; const _Float16* pB2[4];
  const _Float16* eb = dph + (size_t)e * HDIM * IDIM;
#pragma unroll
  for (int c = 0; c < 4; c++) {
    pA2[c] = hbuf + (size_t)(row0 + c * 32 + (tid >> 3)) * IDIM + kc;
    pB2[c] = eb + (size_t)(cb * 128 + c * 32 + (tid >> 3)) * IDIM + kc;
  }

#define STG2(bf, kt) { \
  _Pragma("unroll") for (int c_ = 0; c_ < 4; c_++) { \
    async16(pA2[c_] + (kt)*TK, smem + (bf)*16384 + c_*2048 + tid*8); \
    async16(pB2[c_] + (kt)*TK, smem + (bf)*16384 + 8192 + c_*2048 + tid*8); } }

  const int NIT2 = IDIM / TK;  // 22
  STG2(0, 0); STG2(1, 1);
  WAITVM(8); BAR();
#pragma unroll 1
  for (int kt = 0; kt < NIT2; ++kt) {
    const uint32_t BO = (kt & 1) ? 32768u : 0u;
#pragma unroll
    for (int m_ = 0; m_ < 4; m_++) {
      va2[m_][0] = LDV(sA_0 + BO + m_ * 2048);
      va2[m_][1] = LDV(sA_1 + BO + m_ * 2048);
    }
#pragma unroll
    for (int n_ = 0; n_ < 4; n_++) {
      vb2[n_][0] = LDV(sB_0 + BO + n_ * 2048);
      vb2[n_][1] = LDV(sB_1 + BO + n_ * 2048);
    }
    asm volatile("s_waitcnt lgkmcnt(0)" ::: "memory");
    BAR();
    if (kt + 2 < NIT2) { STG2((kt & 1), kt + 2); }
    PRIO(1);
#pragma unroll
    for (int k_ = 0; k_ < 2; k_++)
#pragma unroll
      for (int m_ = 0; m_ < 4; m_++)
#pragma unroll
        for (int n_ = 0; n_ < 4; n_++)
          acc2[m_][n_] = __builtin_amdgcn_mfma_f32_16x16x32_f16(
              va2[m_][k_], vb2[n_][k_], acc2[m_][n_], 0, 0, 0);
    PRIO(0);
    if (kt + 2 < NIT2) { WAITVM(8); } else { WAITVM(0); }
    BAR();
  }
#undef STG2

#pragma unroll
  for (int mf = 0; mf < 4; mf++) {
#pragma unroll
    for (int r2 = 0; r2 < 4; r2++) {
      const int row = row0 + wm * 64 + mf * 16 + quad * 4 + r2;
      const float wgt = wrow[row];  // pad rows: garbage weight, rows never read back
      _Float16* orow = yh + (size_t)row * HDIM + cb * 128 + wn * 64;
#pragma unroll
      for (int nf = 0; nf < 4; nf++)
        orow[nf * 16 + l15] = (_Float16)(acc2[mf][nf][r2] * wgt);
    }
  }
}

// out[t, :] = y[rowA(t), :] + y[rowB(t), :]
extern "C" __global__ void moe_combine(const _Float16* __restrict__ yh,
                                       const int* __restrict__ rows,
                                       float* __restrict__ out) {
  int i = blockIdx.x * 256 + threadIdx.x;  // over T*H/8 = 524288
  int t = i >> 7, c8 = i & 127;
  int rA = rows[t * 2], rB = rows[t * 2 + 1];
  union { uint4 u; _Float16 h[8]; } pa, pb;
  pa.u = ((const uint4*)(yh + (size_t)rA * HDIM))[c8];
  pb.u = ((const uint4*)(yh + (size_t)rB * HDIM))[c8];
  float4 o0, o1;
  o0.x = (float)pa.h[0] + (float)pb.h[0]; o0.y = (float)pa.h[1] + (float)pb.h[1];
  o0.z = (float)pa.h[2] + (float)pb.h[2]; o0.w = (float)pa.h[3] + (float)pb.h[3];
  o1.x = (float)pa.h[4] + (float)pb.h[4]; o1.y = (float)pa.h[5] + (float)pb.h[5];
  o1.z = (float)pa.h[6] + (float)pb.h[6]; o1.w = (float)pa.h[7] + (float)pb.h[7];
  ((float4*)out)[(size_t)i * 2] = o0;
  ((float4*)out)[(size_t)i * 2 + 1] = o1;
}

extern "C" void kernel_launch(void* const* d_in, const int* in_sizes, int n_in,
                              void* d_out, int out_size, void* d_ws, size_t ws_size,
                              hipStream_t stream) {
  const float* x   = (const float*)d_in[0];  // [4096,1024]
  const float* rw  = (const float*)d_in[1];  // [8,1024]
  const float* gup = (const float*)d_in[2];  // [8,2816,1024]
  const float* dp  = (const float*)d_in[3];  // [8,1024,1408]
  float* out = (float*)d_out;

  char* ws = (char*)d_ws;
  int*   counts   = (int*)ws;                     // 8 ints @0
  int*   cnt_part = (int*)(ws + 64);              // 128 ints
  int*   topi   = (int*)(ws + 4096);              // 8192 ints
  float* topw   = (float*)(ws + 36864);           // 8192 floats
  int*   tok    = (int*)(ws + 69632);             // 10240 ints  -> 110592
  float* wrow   = (float*)(ws + 110592);          // 10240 floats-> 151552
  int*   rows   = (int*)(ws + 151552);            // 8192 ints   -> 184320
  _Float16* xh   = (_Float16*)(ws + 184320);      // 8.39 MB  -> 8572928
  _Float16* guph = (_Float16*)(ws + 8572928);     // 46.14 MB -> 54710272
  _Float16* dph  = (_Float16*)(ws + 54710272);    // 23.07 MB -> 77778944
  _Float16* hbuf = (_Float16*)(ws + 77778944);    // 28.84 MB -> 106614784 (total 106.6 MB)
  _Float16* yh   = (_Float16*)(ws + 8572928);     // aliases guph (dead after gemm1)

  moe_rcv<<<RT_BLKS + CVG_BLKS, 256, 0, stream>>>(x, rw, topi, topw, xh, gup, guph);
  moe_count<<<NTOK / 256, 256, 0, stream>>>(topi, cnt_part);
  moe_scatter<<<NTOK / 256, 256, 0, stream>>>(topi, topw, cnt_part, counts, tok, wrow, rows);
  moe_gemm1cd<<<G1_BLKS + CVD_BLKS, 512, 0, stream>>>(xh, guph, counts, tok, hbuf, dp, dph);
  moe_gemm2<<<8 * 8 * 10, 256, 0, stream>>>(hbuf, dph, counts, wrow, yh);
  moe_combine<<<NTOK * HDIM / 8 / 256, 256, 0, stream>>>(yh, rows, out);
}